// Round 2
// baseline (371.865 us; speedup 1.0000x reference)
//
#include <hip/hip_runtime.h>
#include <math.h>

#define BB 8192      // batch
#define CC 1000      // classes
#define NN 9192      // B + C columns
#define DD 128       // feature dim
#define BM 64        // rows per block
#define BN 64        // cols per chunk
#define NSPLIT 6     // column splits across blockIdx.y
#define NCHUNK 144   // ceil(NN/BN)
#define K2F 14.426950408889634f   // (1/T) * log2(e) = 10*log2(e)

// ---- workspace layout (float offsets) ----
#define WS_BSUM   0        // [64]   per-block lp sums (32 used)
#define WS_CLS    64       // [1024] int  batch histogram
#define WS_TCOL   1088     // [9216] int  t_all
#define WS_RCP0   10304    // [9216] 1/cls_count
#define WS_RCP1   19520    // [9216] 1/(cls_count-1)
#define WS_SPART  28736    // [6*8192]
#define WS_PPART  77888    // [6*8192]

__global__ void hist_kernel(const int* __restrict__ tgt, int* __restrict__ cls) {
    int i = blockIdx.x * blockDim.x + threadIdx.x;
    if (i < BB) atomicAdd(&cls[tgt[i]], 1);
}

__global__ void prep_cols_kernel(const int* __restrict__ tgt, const int* __restrict__ cls,
                                 int* __restrict__ tcol, float* __restrict__ rcp0,
                                 float* __restrict__ rcp1) {
    int j = blockIdx.x * blockDim.x + threadIdx.x;
    if (j >= 9216) return;
    if (j < NN) {
        int c = (j < BB) ? tgt[j] : (j - BB);
        int cnt = cls[c] + 1;                 // +1: the class center itself
        tcol[j] = c;
        rcp0[j] = 1.0f / (float)cnt;
        rcp1[j] = (cnt > 1) ? 1.0f / (float)(cnt - 1) : 0.0f;
    } else {
        tcol[j] = -2; rcp0[j] = 0.0f; rcp1[j] = 0.0f;
    }
}

__global__ __launch_bounds__(256) void main_kernel(
    const float* __restrict__ feats, const float* __restrict__ ctrs,
    const int* __restrict__ tcol, const float* __restrict__ rcp0,
    const float* __restrict__ rcp1,
    float* __restrict__ S_part, float* __restrict__ P_part)
{
    __shared__ float As[DD * BM];     // [k][r], stride 64
    __shared__ float Bs[64 * 66];     // [k(half)][c], stride 66 (pad: conflict-light)

    const int tid = threadIdx.x;
    const int tx = tid & 15;          // column group
    const int ty = tid >> 4;          // row group
    const int row0 = blockIdx.x * BM;
    const int split = blockIdx.y;

    // ---- stage A tile: 64 rows x 128 k, transposed to [k][r] ----
    for (int idx = tid; idx < (BM * DD) / 4; idx += 256) {
        int r = idx >> 5;             // 32 float4 per row
        int k4 = idx & 31;
        const float4 v = *(const float4*)&feats[(size_t)(row0 + r) * DD + k4 * 4];
        As[(k4 * 4 + 0) * BM + r] = v.x;
        As[(k4 * 4 + 1) * BM + r] = v.y;
        As[(k4 * 4 + 2) * BM + r] = v.z;
        As[(k4 * 4 + 3) * BM + r] = v.w;
    }

    int trow[4];
#pragma unroll
    for (int rr = 0; rr < 4; ++rr) trow[rr] = tcol[row0 + 4 * ty + rr];

    float Sacc[4] = {0.f, 0.f, 0.f, 0.f};
    float Pacc[4] = {0.f, 0.f, 0.f, 0.f};

    for (int ch = split; ch < NCHUNK; ch += NSPLIT) {
        const int j0 = ch * BN;

        // prefetch per-column metadata
        int tj[4]; float r0v[4], r1v[4];
#pragma unroll
        for (int cc = 0; cc < 4; ++cc) {
            int j = j0 + 4 * tx + cc;
            bool v = (j < NN);
            tj[cc]  = v ? tcol[j] : -3;
            r0v[cc] = v ? rcp0[j] : 0.f;
            r1v[cc] = v ? rcp1[j] : 0.f;
        }

        float acc[4][4] = {};
#pragma unroll
        for (int half = 0; half < 2; ++half) {
            __syncthreads();
            // stage B half-tile: 64 cols x 64 k, transposed to [k][c]
            for (int idx = tid; idx < (BN * 64) / 4; idx += 256) {
                int c = idx >> 4;     // 16 float4 per col
                int k4 = idx & 15;
                int j = j0 + c;
                float4 v = make_float4(0.f, 0.f, 0.f, 0.f);
                if (j < NN) {
                    const float* src = (j < BB) ? &feats[(size_t)j * DD]
                                                : &ctrs[(size_t)(j - BB) * DD];
                    v = *(const float4*)&src[half * 64 + k4 * 4];
                }
                Bs[(k4 * 4 + 0) * 66 + c] = v.x;
                Bs[(k4 * 4 + 1) * 66 + c] = v.y;
                Bs[(k4 * 4 + 2) * 66 + c] = v.z;
                Bs[(k4 * 4 + 3) * 66 + c] = v.w;
            }
            __syncthreads();

            const int kb = half * 64;
#pragma unroll 8
            for (int k = 0; k < 64; ++k) {
                const float4 a = *(const float4*)&As[(kb + k) * BM + 4 * ty];
                const float2 b0 = *(const float2*)&Bs[k * 66 + 4 * tx];
                const float2 b1 = *(const float2*)&Bs[k * 66 + 4 * tx + 2];
                const float av[4] = {a.x, a.y, a.z, a.w};
                const float bv[4] = {b0.x, b0.y, b1.x, b1.y};
#pragma unroll
                for (int rr = 0; rr < 4; ++rr)
#pragma unroll
                    for (int cc = 0; cc < 4; ++cc)
                        acc[rr][cc] = fmaf(av[rr], bv[cc], acc[rr][cc]);
            }
        }

        // ---- fused epilogue: logits in log2 domain, shift = 1/T ----
#pragma unroll
        for (int cc = 0; cc < 4; ++cc) {
            const int j = j0 + 4 * tx + cc;
            const bool valid = (j < NN);
#pragma unroll
            for (int rr = 0; rr < 4; ++rr) {
                const int i = row0 + 4 * ty + rr;
                const float l2 = fmaf(acc[rr][cc], K2F, -K2F);   // (raw/T - 10)*log2e
                const bool self = (j == i);
                const bool m = (tj[cc] == trow[rr]) && !self;
                const float e = (valid && !self) ? exp2f(l2) : 0.f;
                Sacc[rr] += e * (m ? r1v[cc] : r0v[cc]);
                Pacc[rr] += m ? l2 : 0.f;
            }
        }
    }

    // reduce S/P across the 16 tx lanes of each ty group (tree, deterministic)
#pragma unroll
    for (int off = 1; off < 16; off <<= 1) {
#pragma unroll
        for (int rr = 0; rr < 4; ++rr) {
            Sacc[rr] += __shfl_xor(Sacc[rr], off, 64);
            Pacc[rr] += __shfl_xor(Pacc[rr], off, 64);
        }
    }
    if (tx == 0) {
#pragma unroll
        for (int rr = 0; rr < 4; ++rr) {
            const int i = row0 + 4 * ty + rr;
            S_part[split * BB + i] = Sacc[rr];
            P_part[split * BB + i] = Pacc[rr];
        }
    }
}

__global__ void finalize_kernel(const int* __restrict__ cls, const int* __restrict__ tcol,
                                const float* __restrict__ S_part, const float* __restrict__ P_part,
                                float* __restrict__ bsum)
{
    const int i = blockIdx.x * 256 + threadIdx.x;
    float S = 0.f, P = 0.f;
#pragma unroll
    for (int s = 0; s < NSPLIT; ++s) {
        S += S_part[s * BB + i];
        P += P_part[s * BB + i];
    }
    const float npos = (float)cls[tcol[i]];        // cls_count - 1 == batch histogram
    float lp = P / npos - log2f(S);                // still in log2 units

    // block tree-reduce
    float v = lp;
#pragma unroll
    for (int off = 1; off < 64; off <<= 1) v += __shfl_xor(v, off, 64);
    __shared__ float wsum[4];
    if ((threadIdx.x & 63) == 0) wsum[threadIdx.x >> 6] = v;
    __syncthreads();
    if (threadIdx.x == 0) bsum[blockIdx.x] = wsum[0] + wsum[1] + wsum[2] + wsum[3];
}

__global__ void out_kernel(const float* __restrict__ bsum, float* __restrict__ out) {
    const int t = threadIdx.x;   // 64 threads
    float v = (t < 32) ? bsum[t] : 0.f;
#pragma unroll
    for (int off = 1; off < 64; off <<= 1) v += __shfl_xor(v, off, 64);
    if (t == 0) out[0] = -0.6931471805599453f * (v / (float)BB);   // ln2 * mean, negated
}

extern "C" void kernel_launch(void* const* d_in, const int* in_sizes, int n_in,
                              void* d_out, int out_size, void* d_ws, size_t ws_size,
                              hipStream_t stream) {
    const float* ctrs  = (const float*)d_in[0];   // centers1 [1000,128]
    const float* feats = (const float*)d_in[1];   // features [8192,128]
    const int*   tgt   = (const int*)d_in[2];     // targets  [8192] (harness: integer -> int32)
    float* out = (float*)d_out;
    float* ws  = (float*)d_ws;

    int*   cls  = (int*)(ws + WS_CLS);
    int*   tcol = (int*)(ws + WS_TCOL);
    float* rcp0 = ws + WS_RCP0;
    float* rcp1 = ws + WS_RCP1;
    float* Sp   = ws + WS_SPART;
    float* Pp   = ws + WS_PPART;
    float* bsum = ws + WS_BSUM;

    // zero bsum + cls histogram (ws is poisoned, not re-poisoned between replays)
    hipMemsetAsync(d_ws, 0, (64 + 1024) * sizeof(float), stream);
    hist_kernel<<<dim3(BB / 256), dim3(256), 0, stream>>>(tgt, cls);
    prep_cols_kernel<<<dim3(36), dim3(256), 0, stream>>>(tgt, cls, tcol, rcp0, rcp1);
    main_kernel<<<dim3(BB / BM, NSPLIT), dim3(256), 0, stream>>>(feats, ctrs, tcol, rcp0, rcp1, Sp, Pp);
    finalize_kernel<<<dim3(BB / 256), dim3(256), 0, stream>>>(cls, tcol, Sp, Pp, bsum);
    out_kernel<<<dim3(1), dim3(64), 0, stream>>>(bsum, out);
}

// Round 4
// 101.407 us; speedup vs baseline: 3.6671x; 3.6671x over previous
//
#include <hip/hip_runtime.h>
#include <math.h>

typedef __attribute__((ext_vector_type(8))) short short8;
typedef __attribute__((ext_vector_type(4))) float f32x4;

#define BB 8192      // batch
#define CC 1000      // classes
#define NN 9192      // B + C real columns
#define NPAD 9216    // padded to 72*128
#define DD 128       // feature dim
#define BT 128       // block tile edge
#define NSPLIT 8     // column splits
#define NCH 72       // NPAD / BT
#define K2F 14.426950408889634f   // (1/T) * log2(e)

// ---- workspace layout (float offsets) ----
#define WS_BSUM  0        // [64]
#define WS_CLS   64       // [1024] int
#define WS_TCOL  1088     // [9216] int
#define WS_RCP0  10304    // [9216]
#define WS_RCP1  19520    // [9216]
#define WS_SPART 28736    // [8*8192]
#define WS_PPART 94272    // [8*8192]
#define WS_FBF   159808   // [9216*128] ushort (bf16)

static __device__ __forceinline__ unsigned short f2bf(float x) {
    unsigned int b = __float_as_uint(x);
    unsigned int r = (b + 0x7FFFu + ((b >> 16) & 1u)) >> 16;   // RNE
    return (unsigned short)r;
}

__global__ void hist_kernel(const int* __restrict__ tgt, int* __restrict__ cls) {
    int i = blockIdx.x * blockDim.x + threadIdx.x;
    if (i < BB) atomicAdd(&cls[tgt[i]], 1);
}

__global__ void prep_cols_kernel(const int* __restrict__ tgt, const int* __restrict__ cls,
                                 int* __restrict__ tcol, float* __restrict__ rcp0,
                                 float* __restrict__ rcp1) {
    int j = blockIdx.x * blockDim.x + threadIdx.x;
    if (j >= NPAD) return;
    if (j < NN) {
        int c = (j < BB) ? tgt[j] : (j - BB);
        int cnt = cls[c] + 1;                 // +1: the class center itself
        tcol[j] = c;
        rcp0[j] = 1.0f / (float)cnt;
        rcp1[j] = (cnt > 1) ? 1.0f / (float)(cnt - 1) : 0.0f;
    } else {
        tcol[j] = -2; rcp0[j] = 0.0f; rcp1[j] = 0.0f;
    }
}

__global__ void cvt_kernel(const float* __restrict__ feats, const float* __restrict__ ctrs,
                           unsigned short* __restrict__ F) {
    int idx = blockIdx.x * 256 + threadIdx.x;      // one per 4 elements
    if (idx >= NPAD * DD / 4) return;
    int j = idx >> 5, k4 = idx & 31;
    float4 v = make_float4(0.f, 0.f, 0.f, 0.f);
    if (j < BB)      v = *(const float4*)&feats[(size_t)j * DD + k4 * 4];
    else if (j < NN) v = *(const float4*)&ctrs[(size_t)(j - BB) * DD + k4 * 4];
    ushort4 o;
    o.x = f2bf(v.x); o.y = f2bf(v.y); o.z = f2bf(v.z); o.w = f2bf(v.w);
    *(ushort4*)&F[(size_t)j * DD + k4 * 4] = o;
}

__global__ __launch_bounds__(256) void main_kernel(
    const unsigned short* __restrict__ F, const int* __restrict__ tcol,
    const float* __restrict__ rcp0, const float* __restrict__ rcp1,
    float* __restrict__ S_part, float* __restrict__ P_part)
{
    __shared__ unsigned short Alds[BT * DD];   // [row][k] bf16, XOR-swizzled 16B units
    __shared__ unsigned short Blds[BT * DD];

    const int tid  = threadIdx.x;
    const int lane = tid & 63;
    const int wave = tid >> 6;
    const int wr = wave >> 1, wc = wave & 1;   // 2x2 wave grid, 64x64 each
    const int l15 = lane & 15, l4 = lane >> 4;
    const int row0 = blockIdx.x * BT;
    const int split = blockIdx.y;

    // ---- stage A tile once (swizzled) ----
    for (int t = tid; t < BT * 16; t += 256) {
        int r = t >> 4, k16 = t & 15;
        uint4 v = *(const uint4*)&F[(size_t)(row0 + r) * DD + k16 * 8];
        *(uint4*)((char*)Alds + r * 256 + ((k16 * 16) ^ ((r & 7) << 4))) = v;
    }

    // per-lane row metadata (16 rows per lane: fm x q)
    int ti[16];
#pragma unroll
    for (int fm = 0; fm < 4; ++fm)
#pragma unroll
        for (int q = 0; q < 4; ++q)
            ti[fm * 4 + q] = tcol[row0 + wr * 64 + fm * 16 + l4 * 4 + q];

    float Sl[16], Pl[16];
#pragma unroll
    for (int x = 0; x < 16; ++x) { Sl[x] = 0.f; Pl[x] = 0.f; }

    for (int ch = split; ch < NCH; ch += NSPLIT) {
        const int j0 = ch * BT;
        __syncthreads();
        // ---- stage B tile (rows j0..j0+127 of F), swizzled ----
        for (int t = tid; t < BT * 16; t += 256) {
            int c = t >> 4, k16 = t & 15;
            uint4 v = *(const uint4*)&F[(size_t)(j0 + c) * DD + k16 * 8];
            *(uint4*)((char*)Blds + c * 256 + ((k16 * 16) ^ ((c & 7) << 4))) = v;
        }
        __syncthreads();

        // per-lane column metadata (4 cols per lane: fn)
        int tj[4], jv[4]; float r0[4], r1[4];
#pragma unroll
        for (int fn = 0; fn < 4; ++fn) {
            int j = j0 + wc * 64 + fn * 16 + l15;
            jv[fn] = j; tj[fn] = tcol[j]; r0[fn] = rcp0[j]; r1[fn] = rcp1[j];
        }

        f32x4 acc[4][4];
#pragma unroll
        for (int a = 0; a < 4; ++a)
#pragma unroll
            for (int b = 0; b < 4; ++b) acc[a][b] = (f32x4){0.f, 0.f, 0.f, 0.f};

#pragma unroll
        for (int ks = 0; ks < 4; ++ks) {
            short8 af[4], bfr[4];
#pragma unroll
            for (int fm = 0; fm < 4; ++fm) {
                int r = wr * 64 + fm * 16 + l15;
                af[fm] = *(const short8*)((const char*)Alds + r * 256 +
                                          ((ks * 64 + l4 * 16) ^ ((r & 7) << 4)));
            }
#pragma unroll
            for (int fn = 0; fn < 4; ++fn) {
                int c = wc * 64 + fn * 16 + l15;
                bfr[fn] = *(const short8*)((const char*)Blds + c * 256 +
                                           ((ks * 64 + l4 * 16) ^ ((c & 7) << 4)));
            }
#pragma unroll
            for (int fm = 0; fm < 4; ++fm)
#pragma unroll
                for (int fn = 0; fn < 4; ++fn)
                    acc[fm][fn] = __builtin_amdgcn_mfma_f32_16x16x32_bf16(
                        af[fm], bfr[fn], acc[fm][fn], 0, 0, 0);
        }

        // ---- fused epilogue (log2 domain, fixed shift 1/T) ----
#pragma unroll
        for (int fm = 0; fm < 4; ++fm) {
#pragma unroll
            for (int q = 0; q < 4; ++q) {
                const int i = row0 + wr * 64 + fm * 16 + l4 * 4 + q;
                const int t_i = ti[fm * 4 + q];
                float s_add = 0.f, p_add = 0.f;
#pragma unroll
                for (int fn = 0; fn < 4; ++fn) {
                    float d = acc[fm][fn][q];
                    float l2 = fmaf(d, K2F, -K2F);       // (dot/T - 10)*log2e
                    bool self = (jv[fn] == i);
                    bool m = (tj[fn] == t_i) && !self;
                    float e = self ? 0.f : exp2f(l2);
                    s_add += e * (m ? r1[fn] : r0[fn]);  // padded cols: rcp=0
                    p_add += m ? l2 : 0.f;
                }
                Sl[fm * 4 + q] += s_add;
                Pl[fm * 4 + q] += p_add;
            }
        }
    }

    // ---- reduce across 16 column-lanes (tree), then combine the two wc waves
    //      that share the same output rows via LDS (fixes cross-wave race) ----
    __syncthreads();                       // done with Alds this round
    float* Sx = (float*)Alds;              // [128] per-block row scratch
    float* Px = ((float*)Alds) + 128;      // [128]

#pragma unroll
    for (int idx = 0; idx < 16; ++idx) {
        float S = Sl[idx], P = Pl[idx];
#pragma unroll
        for (int off = 1; off < 16; off <<= 1) {
            S += __shfl_xor(S, off, 64);
            P += __shfl_xor(P, off, 64);
        }
        Sl[idx] = S; Pl[idx] = P;          // lane l15==0 holds the row sum
        if (wc == 1 && l15 == 0) {
            int rl = wr * 64 + (idx >> 2) * 16 + l4 * 4 + (idx & 3);
            Sx[rl] = S; Px[rl] = P;
        }
    }
    __syncthreads();
    if (wc == 0 && l15 == 0) {
#pragma unroll
        for (int idx = 0; idx < 16; ++idx) {
            int rl = wr * 64 + (idx >> 2) * 16 + l4 * 4 + (idx & 3);
            int row = row0 + rl;
            S_part[split * BB + row] = Sl[idx] + Sx[rl];
            P_part[split * BB + row] = Pl[idx] + Px[rl];
        }
    }
}

__global__ void finalize_kernel(const int* __restrict__ cls, const int* __restrict__ tcol,
                                const float* __restrict__ S_part, const float* __restrict__ P_part,
                                float* __restrict__ bsum)
{
    const int i = blockIdx.x * 256 + threadIdx.x;
    float S = 0.f, P = 0.f;
#pragma unroll
    for (int s = 0; s < NSPLIT; ++s) {
        S += S_part[s * BB + i];
        P += P_part[s * BB + i];
    }
    const float npos = (float)cls[tcol[i]];   // = row mask count
    float lp = P / npos - log2f(S);           // log2 units

    float v = lp;
#pragma unroll
    for (int off = 1; off < 64; off <<= 1) v += __shfl_xor(v, off, 64);
    __shared__ float wsum[4];
    if ((threadIdx.x & 63) == 0) wsum[threadIdx.x >> 6] = v;
    __syncthreads();
    if (threadIdx.x == 0) bsum[blockIdx.x] = wsum[0] + wsum[1] + wsum[2] + wsum[3];
}

__global__ void out_kernel(const float* __restrict__ bsum, float* __restrict__ out) {
    const int t = threadIdx.x;   // 64 threads
    float v = (t < 32) ? bsum[t] : 0.f;
#pragma unroll
    for (int off = 1; off < 64; off <<= 1) v += __shfl_xor(v, off, 64);
    if (t == 0) out[0] = -0.6931471805599453f * (v / (float)BB);   // ln2 * mean, negated
}

extern "C" void kernel_launch(void* const* d_in, const int* in_sizes, int n_in,
                              void* d_out, int out_size, void* d_ws, size_t ws_size,
                              hipStream_t stream) {
    const float* ctrs  = (const float*)d_in[0];   // centers1 [1000,128]
    const float* feats = (const float*)d_in[1];   // features [8192,128]
    const int*   tgt   = (const int*)d_in[2];     // targets  [8192] int32
    float* out = (float*)d_out;
    float* ws  = (float*)d_ws;

    int*   cls  = (int*)(ws + WS_CLS);
    int*   tcol = (int*)(ws + WS_TCOL);
    float* rcp0 = ws + WS_RCP0;
    float* rcp1 = ws + WS_RCP1;
    float* Sp   = ws + WS_SPART;
    float* Pp   = ws + WS_PPART;
    float* bsum = ws + WS_BSUM;
    unsigned short* F = (unsigned short*)(ws + WS_FBF);

    hipMemsetAsync(d_ws, 0, (64 + 1024) * sizeof(float), stream);
    hist_kernel<<<dim3(BB / 256), dim3(256), 0, stream>>>(tgt, cls);
    prep_cols_kernel<<<dim3(NPAD / 256), dim3(256), 0, stream>>>(tgt, cls, tcol, rcp0, rcp1);
    cvt_kernel<<<dim3(NPAD * DD / 4 / 256), dim3(256), 0, stream>>>(feats, ctrs, F);
    main_kernel<<<dim3(BB / BT, NSPLIT), dim3(256), 0, stream>>>(F, tcol, rcp0, rcp1, Sp, Pp);
    finalize_kernel<<<dim3(BB / 256), dim3(256), 0, stream>>>(cls, tcol, Sp, Pp, bsum);
    out_kernel<<<dim3(1), dim3(64), 0, stream>>>(bsum, out);
}

// Round 5
// 68.083 us; speedup vs baseline: 5.4620x; 1.4895x over previous
//
#include <hip/hip_runtime.h>
#include <math.h>

typedef __attribute__((ext_vector_type(8))) short short8;
typedef __attribute__((ext_vector_type(4))) float f32x4;
typedef __attribute__((address_space(3))) unsigned int lds_u32;
typedef const __attribute__((address_space(1))) unsigned int glb_u32;

#define BB 8192      // batch
#define CC 1000      // classes
#define NN 9192      // B + C real columns
#define NPAD 9216    // padded to 72*128
#define DD 128       // feature dim
#define BT 128       // block tile edge
#define NSPLIT 8     // column splits
#define NCH 72       // NPAD / BT
#define NT 9         // chunks per split
#define K2F 14.426950408889634f   // (1/T) * log2(e)

// ---- workspace layout (float offsets) ----
#define WS_BSUM  0        // [64]
#define WS_CLS   64       // [1024] int
#define WS_TCOL  1088     // [9216] int
#define WS_RCP0  10304    // [9216]
#define WS_RCP1  19520    // [9216]
#define WS_SPART 28736    // [8*8192]
#define WS_PPART 94272    // [8*8192]
#define WS_FBF   159808   // [9216*128] ushort (bf16)

static __device__ __forceinline__ unsigned short f2bf(float x) {
    unsigned int b = __float_as_uint(x);
    unsigned int r = (b + 0x7FFFu + ((b >> 16) & 1u)) >> 16;   // RNE
    return (unsigned short)r;
}

__global__ void hist_kernel(const int* __restrict__ tgt, int* __restrict__ cls) {
    int i = blockIdx.x * blockDim.x + threadIdx.x;
    if (i < BB) atomicAdd(&cls[tgt[i]], 1);
}

__global__ void prep_cols_kernel(const int* __restrict__ tgt, const int* __restrict__ cls,
                                 int* __restrict__ tcol, float* __restrict__ rcp0,
                                 float* __restrict__ rcp1) {
    int j = blockIdx.x * blockDim.x + threadIdx.x;
    if (j >= NPAD) return;
    if (j < NN) {
        int c = (j < BB) ? tgt[j] : (j - BB);
        int cnt = cls[c] + 1;                 // +1: the class center itself
        tcol[j] = c;
        rcp0[j] = 1.0f / (float)cnt;
        rcp1[j] = (cnt > 1) ? 1.0f / (float)(cnt - 1) : 0.0f;
    } else {
        tcol[j] = -2; rcp0[j] = 0.0f; rcp1[j] = 0.0f;
    }
}

__global__ void cvt_kernel(const float* __restrict__ feats, const float* __restrict__ ctrs,
                           unsigned short* __restrict__ F) {
    int idx = blockIdx.x * 256 + threadIdx.x;      // one per 4 elements
    if (idx >= NPAD * DD / 4) return;
    int j = idx >> 5, k4 = idx & 31;
    float4 v = make_float4(0.f, 0.f, 0.f, 0.f);
    if (j < BB)      v = *(const float4*)&feats[(size_t)j * DD + k4 * 4];
    else if (j < NN) v = *(const float4*)&ctrs[(size_t)(j - BB) * DD + k4 * 4];
    ushort4 o;
    o.x = f2bf(v.x); o.y = f2bf(v.y); o.z = f2bf(v.z); o.w = f2bf(v.w);
    *(ushort4*)&F[(size_t)j * DD + k4 * 4] = o;
}

// Stage 128 rows x 256B of F into an LDS buffer: linear LDS dest (global_load_lds
// requirement), inverse-swizzled GLOBAL source so that a swizzled ds_read
// (byte ^ ((row&7)<<4)) returns linear data. Each wave covers 8 x 1KB segments.
static __device__ __forceinline__ void stage_tile(const unsigned short* __restrict__ F,
                                                  int row_base, unsigned short* buf,
                                                  int wave, int lane) {
#pragma unroll
    for (int it = 0; it < 8; ++it) {
        const int seg = wave * 8 + it;          // 0..31
        const int r   = seg * 4 + (lane >> 4);  // tile row 0..127
        const int b   = (lane & 15) * 16;       // byte within row
        const char* g = (const char*)F + (size_t)(row_base + r) * 256 + (b ^ ((r & 7) << 4));
        unsigned short* l = buf + seg * 512;    // wave-uniform base; HW adds lane*16
        __builtin_amdgcn_global_load_lds((glb_u32*)g, (lds_u32*)l, 16, 0, 0);
    }
}

__global__ __launch_bounds__(256, 2) void main_kernel(
    const unsigned short* __restrict__ F, const int* __restrict__ tcol,
    const float* __restrict__ rcp0, const float* __restrict__ rcp1,
    float* __restrict__ S_part, float* __restrict__ P_part)
{
    __shared__ unsigned short Bds[2][BT * DD];   // 2 x 32KB double buffer

    const int tid  = threadIdx.x;
    const int lane = tid & 63;
    const int wave = tid >> 6;
    const int wr = wave >> 1, wc = wave & 1;     // 2x2 wave grid, 64x64 each
    const int l15 = lane & 15, l4 = lane >> 4;
    const int row0 = blockIdx.x * BT;
    const int split = blockIdx.y;

    // ---- A tile -> registers once (via LDS buffer 0) ----
    stage_tile(F, row0, Bds[0], wave, lane);
    __syncthreads();
    short8 af[4][4];                             // [ks][fm]
#pragma unroll
    for (int ks = 0; ks < 4; ++ks)
#pragma unroll
        for (int fm = 0; fm < 4; ++fm) {
            int r = wr * 64 + fm * 16 + l15;
            af[ks][fm] = *(const short8*)((const char*)Bds[0] + r * 256 +
                                          ((ks * 64 + l4 * 16) ^ ((r & 7) << 4)));
        }
    __syncthreads();                             // all reads done before overwrite

    // per-lane row metadata (16 rows per lane: fm x q)
    int ti[16];
#pragma unroll
    for (int fm = 0; fm < 4; ++fm)
#pragma unroll
        for (int q = 0; q < 4; ++q)
            ti[fm * 4 + q] = tcol[row0 + wr * 64 + fm * 16 + l4 * 4 + q];

    float Sl[16], Pl[16];
#pragma unroll
    for (int x = 0; x < 16; ++x) { Sl[x] = 0.f; Pl[x] = 0.f; }

    // ---- prologue: stage chunk 0 ----
    stage_tile(F, split * BT, Bds[0], wave, lane);
    __syncthreads();

    int cur = 0;
#pragma unroll 1
    for (int t = 0; t < NT; ++t) {
        const int j0 = (split + t * NSPLIT) * BT;
        if (t + 1 < NT)                          // issue next-tile loads early
            stage_tile(F, (split + (t + 1) * NSPLIT) * BT, Bds[cur ^ 1], wave, lane);

        // per-lane column metadata (lands during MFMA phase)
        int tj[4]; float r0[4], r1[4];
#pragma unroll
        for (int fn = 0; fn < 4; ++fn) {
            int j = j0 + wc * 64 + fn * 16 + l15;
            tj[fn] = tcol[j]; r0[fn] = rcp0[j]; r1[fn] = rcp1[j];
        }

        f32x4 acc[4][4];
#pragma unroll
        for (int a = 0; a < 4; ++a)
#pragma unroll
            for (int b = 0; b < 4; ++b) acc[a][b] = (f32x4){0.f, 0.f, 0.f, 0.f};

#pragma unroll
        for (int ks = 0; ks < 4; ++ks) {
            short8 bfr[4];
#pragma unroll
            for (int fn = 0; fn < 4; ++fn) {
                int c = wc * 64 + fn * 16 + l15;
                bfr[fn] = *(const short8*)((const char*)Bds[cur] + c * 256 +
                                           ((ks * 64 + l4 * 16) ^ ((c & 7) << 4)));
            }
#pragma unroll
            for (int fm = 0; fm < 4; ++fm)
#pragma unroll
                for (int fn = 0; fn < 4; ++fn)
                    acc[fm][fn] = __builtin_amdgcn_mfma_f32_16x16x32_bf16(
                        af[ks][fm], bfr[fn], acc[fm][fn], 0, 0, 0);
        }

        // ---- fused epilogue (log2 domain, fixed shift 1/T) ----
#pragma unroll
        for (int fm = 0; fm < 4; ++fm) {
#pragma unroll
            for (int q = 0; q < 4; ++q) {
                const int i = row0 + wr * 64 + fm * 16 + l4 * 4 + q;
                const int t_i = ti[fm * 4 + q];
                float s_add = 0.f, p_add = 0.f;
#pragma unroll
                for (int fn = 0; fn < 4; ++fn) {
                    const int j = j0 + wc * 64 + fn * 16 + l15;
                    float d = acc[fm][fn][q];
                    float l2 = fmaf(d, K2F, -K2F);       // (dot/T - 10)*log2e
                    bool self = (j == i);
                    bool m = (tj[fn] == t_i) && !self;
                    float e = self ? 0.f : exp2f(l2);
                    s_add += e * (m ? r1[fn] : r0[fn]);  // padded cols: rcp=0
                    p_add += m ? l2 : 0.f;
                }
                Sl[fm * 4 + q] += s_add;
                Pl[fm * 4 + q] += p_add;
            }
        }

        __syncthreads();                         // vmcnt(0)+barrier: next tile ready
        cur ^= 1;
    }

    // ---- reduce across 16 column-lanes (tree), combine the two wc waves via LDS ----
    float* Sx = (float*)&Bds[0][0];              // [128] scratch (tiles dead now)
    float* Px = ((float*)&Bds[0][0]) + 128;      // [128]

#pragma unroll
    for (int idx = 0; idx < 16; ++idx) {
        float S = Sl[idx], P = Pl[idx];
#pragma unroll
        for (int off = 1; off < 16; off <<= 1) {
            S += __shfl_xor(S, off, 64);
            P += __shfl_xor(P, off, 64);
        }
        Sl[idx] = S; Pl[idx] = P;                // lane l15==0 holds the row sum
        if (wc == 1 && l15 == 0) {
            int rl = wr * 64 + (idx >> 2) * 16 + l4 * 4 + (idx & 3);
            Sx[rl] = S; Px[rl] = P;
        }
    }
    __syncthreads();
    if (wc == 0 && l15 == 0) {
#pragma unroll
        for (int idx = 0; idx < 16; ++idx) {
            int rl = wr * 64 + (idx >> 2) * 16 + l4 * 4 + (idx & 3);
            int row = row0 + rl;
            S_part[split * BB + row] = Sl[idx] + Sx[rl];
            P_part[split * BB + row] = Pl[idx] + Px[rl];
        }
    }
}

__global__ void finalize_kernel(const int* __restrict__ cls, const int* __restrict__ tcol,
                                const float* __restrict__ S_part, const float* __restrict__ P_part,
                                float* __restrict__ bsum)
{
    const int i = blockIdx.x * 256 + threadIdx.x;
    float S = 0.f, P = 0.f;
#pragma unroll
    for (int s = 0; s < NSPLIT; ++s) {
        S += S_part[s * BB + i];
        P += P_part[s * BB + i];
    }
    const float npos = (float)cls[tcol[i]];   // = row mask count
    float lp = P / npos - log2f(S);           // log2 units

    float v = lp;
#pragma unroll
    for (int off = 1; off < 64; off <<= 1) v += __shfl_xor(v, off, 64);
    __shared__ float wsum[4];
    if ((threadIdx.x & 63) == 0) wsum[threadIdx.x >> 6] = v;
    __syncthreads();
    if (threadIdx.x == 0) bsum[blockIdx.x] = wsum[0] + wsum[1] + wsum[2] + wsum[3];
}

__global__ void out_kernel(const float* __restrict__ bsum, float* __restrict__ out) {
    const int t = threadIdx.x;   // 64 threads
    float v = (t < 32) ? bsum[t] : 0.f;
#pragma unroll
    for (int off = 1; off < 64; off <<= 1) v += __shfl_xor(v, off, 64);
    if (t == 0) out[0] = -0.6931471805599453f * (v / (float)BB);   // ln2 * mean, negated
}

extern "C" void kernel_launch(void* const* d_in, const int* in_sizes, int n_in,
                              void* d_out, int out_size, void* d_ws, size_t ws_size,
                              hipStream_t stream) {
    const float* ctrs  = (const float*)d_in[0];   // centers1 [1000,128]
    const float* feats = (const float*)d_in[1];   // features [8192,128]
    const int*   tgt   = (const int*)d_in[2];     // targets  [8192] int32
    float* out = (float*)d_out;
    float* ws  = (float*)d_ws;

    int*   cls  = (int*)(ws + WS_CLS);
    int*   tcol = (int*)(ws + WS_TCOL);
    float* rcp0 = ws + WS_RCP0;
    float* rcp1 = ws + WS_RCP1;
    float* Sp   = ws + WS_SPART;
    float* Pp   = ws + WS_PPART;
    float* bsum = ws + WS_BSUM;
    unsigned short* F = (unsigned short*)(ws + WS_FBF);

    hipMemsetAsync(d_ws, 0, (64 + 1024) * sizeof(float), stream);
    hist_kernel<<<dim3(BB / 256), dim3(256), 0, stream>>>(tgt, cls);
    prep_cols_kernel<<<dim3(NPAD / 256), dim3(256), 0, stream>>>(tgt, cls, tcol, rcp0, rcp1);
    cvt_kernel<<<dim3(NPAD * DD / 4 / 256), dim3(256), 0, stream>>>(feats, ctrs, F);
    main_kernel<<<dim3(BB / BT, NSPLIT), dim3(256), 0, stream>>>(F, tcol, rcp0, rcp1, Sp, Pp);
    finalize_kernel<<<dim3(BB / 256), dim3(256), 0, stream>>>(cls, tcol, Sp, Pp, bsum);
    out_kernel<<<dim3(1), dim3(64), 0, stream>>>(bsum, out);
}